// Round 13
// baseline (67.631 us; speedup 1.0000x reference)
//
#include <hip/hip_runtime.h>

#define N_NODES 100000
#define E_EDGES 2000000
#define SPLIT_E 1800000   // optimal split: min(2T + 3.8M*e^(-2T/100k)) -> T ~ 182k; 200k edges
#define CIN 16
#define EXH_FLOW 4.0f     // 0.0001 * 40000
#define TOP_E (E_EDGES - SPLIT_E)

#define UNROLL 4
#define ECHUNK (E_EDGES / UNROLL)          // 500000 edges per chunk
#define QTHREADS (E_EDGES * 4 / UNROLL)    // 2M work items: 4 lanes/edge, 4 edges/item

#define BLK 256
#define TOP_BLOCKS    ((TOP_E + BLK - 1) / BLK)       // 782
#define STREAM_BLOCKS ((QTHREADS + BLK - 1) / BLK)    // 7813
#define REST_EPT 8
#define REST_BLOCKS ((SPLIT_E / REST_EPT + BLK - 1) / BLK)

// origin_data: (N, 8, 3) f32; last timestep at n*24 + {21,22,23} = {conc, people, size}

// K1: node init + table init (R5's proven kernel; memset nodes regressed R6,
// bitmap atomics regressed R8, cooperative grid regressed R10).
__global__ void init_nodes_kernel(const float* __restrict__ origin,
                                  float* __restrict__ out,
                                  int* __restrict__ max_ord,
                                  float* __restrict__ conc_c,
                                  float* __restrict__ rsize_c,
                                  unsigned char* __restrict__ settled) {
    int n = blockIdx.x * blockDim.x + threadIdx.x;
    if (n >= N_NODES) return;
    size_t base = (size_t)n * 24;
    float conc   = origin[base + 21];
    float people = origin[base + 22];
    float size   = origin[base + 23];
    float rs = 1.0f / size;
    out[n] = conc + EXH_FLOW * people * rs;
    conc_c[n]  = conc;
    rsize_c[n] = rs;
    max_ord[n] = -1;
    settled[n] = 0;
}

// K2: {top-chunk pure scatter || PURE flow stream} as disjoint block roles.
// Why this co-residency is safe where R7/R11 weren't: the roles share NO
// mutable-read lines. Top role reads only src/dst (private range), writes
// settled (plain byte stores, read by NOBODY here) and max_ord (atomics,
// touched by nobody else here). Stream role reads x/w/b and writes flow —
// it does NO scatter and NO settled reads, so nothing it reads can be
// invalidated by the top role. Settled becomes immutable at this kernel's
// boundary (R11 lesson), ready for K3's pre-checks. Top atomics hide under
// the BW-bound stream; no dependent loads after them -> no R7-style tail.
__global__ void stream_and_top_kernel(const float4* __restrict__ xv,
                                      const float* __restrict__ w,
                                      const float* __restrict__ b,
                                      const int* __restrict__ src,
                                      const int* __restrict__ dst,
                                      float* __restrict__ flow,
                                      int* __restrict__ max_ord,
                                      unsigned char* __restrict__ settled) {
    if (blockIdx.x < TOP_BLOCKS) {
        int e = SPLIT_E + blockIdx.x * BLK + threadIdx.x;
        if (e >= E_EDGES) return;
        int s = src[e], d = dst[e];
        if (s != d) {
            atomicMax(&max_ord[s], 2 * e);
            atomicMax(&max_ord[d], 2 * e + 1);
            settled[s] = 1;   // same-value races benign; marks FINAL at boundary
            settled[d] = 1;
        }
        return;
    }
    // Pure stream: 4 lanes/edge, one float4 each (consecutive lanes ->
    // consecutive 16B), UNROLL-4 chunks for 4x outstanding loads, quad
    // shfl_xor reduce, all-lane flow store (R12 pattern).
    int t = (blockIdx.x - TOP_BLOCKS) * BLK + threadIdx.x;   // [0, 2M)
    if (t >= QTHREADS) return;
    int q  = t & 3;
    int e0 = t >> 2;                      // [0, ECHUNK)
    float4 wq = ((const float4*)w)[q];    // 64B total, L1 broadcast
    float bias = b[0];

    float4 v0 = xv[t + 0 * QTHREADS];
    float4 v1 = xv[t + 1 * QTHREADS];
    float4 v2 = xv[t + 2 * QTHREADS];
    float4 v3 = xv[t + 3 * QTHREADS];

    float p0 = v0.x * wq.x + v0.y * wq.y + v0.z * wq.z + v0.w * wq.w;
    float p1 = v1.x * wq.x + v1.y * wq.y + v1.z * wq.z + v1.w * wq.w;
    float p2 = v2.x * wq.x + v2.y * wq.y + v2.z * wq.z + v2.w * wq.w;
    float p3 = v3.x * wq.x + v3.y * wq.y + v3.z * wq.z + v3.w * wq.w;

    p0 += __shfl_xor(p0, 1);  p0 += __shfl_xor(p0, 2);
    p1 += __shfl_xor(p1, 1);  p1 += __shfl_xor(p1, 2);
    p2 += __shfl_xor(p2, 1);  p2 += __shfl_xor(p2, 2);
    p3 += __shfl_xor(p3, 1);  p3 += __shfl_xor(p3, 2);

    // Branchless static select; lane q stores chunk q (wave covers 4 x 64B).
    float pq = (q == 0) ? p0 : ((q == 1) ? p1 : ((q == 2) ? p2 : p3));
    flow[e0 + q * ECHUNK] = pq + bias;
}

// K3: rest-scatter over [0, SPLIT_E) — pre-check against the now-IMMUTABLE
// settled byte-map (read-only in this dispatch -> L2-hot, never invalidated;
// R4 measured this pattern fine standalone). ~98% deterministic skip; ~70k
// firing atomics hit max_ord. 8 edges/thread via int4 loads for MLP.
__global__ void scatter_rest_kernel(const int* __restrict__ src,
                                    const int* __restrict__ dst,
                                    const unsigned char* __restrict__ settled,
                                    int* __restrict__ max_ord) {
    int t = blockIdx.x * blockDim.x + threadIdx.x;
    int e0 = t * REST_EPT;
    if (e0 >= SPLIT_E) return;
    int4 sa = *(const int4*)(src + e0);
    int4 sb = *(const int4*)(src + e0 + 4);
    int4 da = *(const int4*)(dst + e0);
    int4 db = *(const int4*)(dst + e0 + 4);
#define PROC(EE, SS, DD)                                                  \
    if ((SS) != (DD)) {                                                   \
        if (!settled[SS]) atomicMax(&max_ord[SS], 2 * (EE));              \
        if (!settled[DD]) atomicMax(&max_ord[DD], 2 * (EE) + 1);          \
    }
    PROC(e0 + 0, sa.x, da.x)
    PROC(e0 + 1, sa.y, da.y)
    PROC(e0 + 2, sa.z, da.z)
    PROC(e0 + 3, sa.w, da.w)
    PROC(e0 + 4, sb.x, db.x)
    PROC(e0 + 5, sb.y, db.y)
    PROC(e0 + 6, sb.z, db.z)
    PROC(e0 + 7, sb.w, db.w)
#undef PROC
}

// K4: per-node finalize — decode winning occurrence, gather its value.
__global__ void finalize_kernel(const int* __restrict__ src,
                                const float* __restrict__ flow,
                                const int* __restrict__ max_ord,
                                const float* __restrict__ conc_c,
                                const float* __restrict__ rsize_c,
                                float* __restrict__ out) {
    int n = blockIdx.x * blockDim.x + threadIdx.x;
    if (n >= N_NODES) return;
    int o = max_ord[n];
    if (o < 0) return;
    int e = o >> 1;
    float val = flow[e];
    float v;
    if ((o & 1) == 0) {
        v = val * conc_c[n] * rsize_c[n];            // src-side: src[e]==n
    } else {
        int s = src[e];
        v = val * conc_c[s] * rsize_c[n];            // dst-side
    }
    out[n] += v;
}

extern "C" void kernel_launch(void* const* d_in, const int* in_sizes, int n_in,
                              void* d_out, int out_size, void* d_ws, size_t ws_size,
                              hipStream_t stream) {
    const float* origin = (const float*)d_in[0];   // (N, 8, 3)
    const float* x      = (const float*)d_in[1];   // (E, 1, 16)
    const float* conv_w = (const float*)d_in[2];   // (1, 16, 1, 1)
    const float* conv_b = (const float*)d_in[3];   // (1,)
    const int*   eidx   = (const int*)d_in[4];     // (2, E)
    const int* src = eidx;
    const int* dst = eidx + E_EDGES;

    float* out  = (float*)d_out;          // [0, N): result; [N, N+E): flow
    float* flow = out + N_NODES;

    int*           max_ord = (int*)d_ws;                           // 400 KB
    float*         conc_c  = (float*)((char*)d_ws + 1 * 400 * 1024);
    float*         rsize_c = (float*)((char*)d_ws + 2 * 400 * 1024);
    unsigned char* settled = (unsigned char*)((char*)d_ws + 3 * 400 * 1024); // 100 KB

    init_nodes_kernel<<<(N_NODES + BLK - 1) / BLK, BLK, 0, stream>>>(
        origin, out, max_ord, conc_c, rsize_c, settled);
    stream_and_top_kernel<<<TOP_BLOCKS + STREAM_BLOCKS, BLK, 0, stream>>>(
        (const float4*)x, conv_w, conv_b, src, dst, flow, max_ord, settled);
    scatter_rest_kernel<<<REST_BLOCKS, BLK, 0, stream>>>(
        src, dst, settled, max_ord);
    finalize_kernel<<<(N_NODES + BLK - 1) / BLK, BLK, 0, stream>>>(
        src, flow, max_ord, conc_c, rsize_c, out);
}

// Round 14
// 64.598 us; speedup vs baseline: 1.0470x; 1.0470x over previous
//
#include <hip/hip_runtime.h>

#define N_NODES 100000
#define E_EDGES 2000000
#define SPLIT_E 1800000   // top 10%: 400k touches, P(node untouched) ~ e^-4 ~ 1.8%
#define CIN 16
#define EXH_FLOW 4.0f     // 0.0001 * 40000
#define TOP_E (E_EDGES - SPLIT_E)

#define UNROLL 4
#define ECHUNK (E_EDGES / UNROLL)          // 500000 edges per chunk
#define QTHREADS (E_EDGES * 4 / UNROLL)    // 2M work items: 4 lanes/edge, 4 edges/item

#define BLK 256
#define NODE_BLOCKS ((N_NODES + BLK - 1) / BLK)   // 391
#define TOP_BLOCKS  ((TOP_E + BLK - 1) / BLK)     // 782

// origin_data: (N, 8, 3) f32; last timestep at n*24 + {21,22,23} = {conc, people, size}
//
// FINAL (R12 structure, measured best 64.7 us). Converged after R6-R13
// bracketing: memset nodes (R6), block-role co-residency of scatter with
// stream (R7/R11/R13), bitmap atomics (R8), cooperative persistent grid
// (R10) all regressed; this 4-dispatch chain is the measured Pareto point.

// K0: table init only — wide int4 stores. Separate dispatch: top-chunk
// atomics may not race with these plain stores.
__global__ void table_init_kernel(int4* __restrict__ max_ord4,
                                  uint4* __restrict__ settled4) {
    int i = blockIdx.x * blockDim.x + threadIdx.x;
    if (i < N_NODES / 4) max_ord4[i] = make_int4(-1, -1, -1, -1);
    if (i < N_NODES / 16) settled4[i] = make_uint4(0u, 0u, 0u, 0u);
}

// K1: node-init || top-chunk scatter as disjoint block ranges (disjoint
// arrays -> no hazard; node-init hides under top-scatter atomic latency).
// Top chunk: pure atomics (values unsettled here; R2 lesson) + plain
// byte-store settled marks (same-value races benign). Top orders
// >= 2*SPLIT_E dominate all lower orders -> marks FINAL at boundary.
__global__ void init_and_top_kernel(const float* __restrict__ origin,
                                    const int* __restrict__ src,
                                    const int* __restrict__ dst,
                                    float* __restrict__ out,
                                    float* __restrict__ conc_c,
                                    float* __restrict__ rsize_c,
                                    int* __restrict__ max_ord,
                                    unsigned char* __restrict__ settled) {
    if (blockIdx.x < NODE_BLOCKS) {
        int n = blockIdx.x * BLK + threadIdx.x;
        if (n >= N_NODES) return;
        size_t base = (size_t)n * 24;
        float conc   = origin[base + 21];
        float people = origin[base + 22];
        float size   = origin[base + 23];
        float rs = 1.0f / size;
        out[n] = conc + EXH_FLOW * people * rs;
        conc_c[n]  = conc;
        rsize_c[n] = rs;
    } else {
        int e = SPLIT_E + (blockIdx.x - NODE_BLOCKS) * BLK + threadIdx.x;
        if (e >= E_EDGES) return;
        int s = src[e], d = dst[e];
        if (s != d) {
            atomicMax(&max_ord[s], 2 * e);
            atomicMax(&max_ord[d], 2 * e + 1);
            settled[s] = 1;
            settled[d] = 1;
        }
    }
}

// K2: fused stream + all-lane scatter. 4 lanes/edge, one float4 each
// (consecutive lanes -> consecutive 16B), UNROLL-4 chunks for 4x outstanding
// loads, quad shfl_xor reduce -> all lanes hold p0..p3. Lane q stores flow
// chunk q and handles side (q>>1) of chunks {(q&1), (q&1)+2} — per-lane
// dependent chain is 2 settled gathers. Pre-check target is the IMMUTABLE
// 100 KB byte-map (read-only in this dispatch -> L2-hot; immutability
// requires the kernel boundary — R11). ~66k firing atomics hit max_ord.
__global__ void fused_flow_scatter_kernel(const float4* __restrict__ xv,
                                          const float* __restrict__ w,
                                          const float* __restrict__ b,
                                          const int* __restrict__ src,
                                          const int* __restrict__ dst,
                                          const unsigned char* __restrict__ settled,
                                          float* __restrict__ flow,
                                          int* __restrict__ max_ord) {
    int tid = blockIdx.x * blockDim.x + threadIdx.x;   // [0, 2M)
    if (tid >= QTHREADS) return;
    int q  = tid & 3;
    int e0 = tid >> 2;                    // [0, ECHUNK)
    float4 wq = ((const float4*)w)[q];    // 64B total, L1 broadcast
    float bias = b[0];

    float4 v0 = xv[tid + 0 * QTHREADS];
    float4 v1 = xv[tid + 1 * QTHREADS];
    float4 v2 = xv[tid + 2 * QTHREADS];
    float4 v3 = xv[tid + 3 * QTHREADS];

    float p0 = v0.x * wq.x + v0.y * wq.y + v0.z * wq.z + v0.w * wq.w;
    float p1 = v1.x * wq.x + v1.y * wq.y + v1.z * wq.z + v1.w * wq.w;
    float p2 = v2.x * wq.x + v2.y * wq.y + v2.z * wq.z + v2.w * wq.w;
    float p3 = v3.x * wq.x + v3.y * wq.y + v3.z * wq.z + v3.w * wq.w;

    p0 += __shfl_xor(p0, 1);  p0 += __shfl_xor(p0, 2);
    p1 += __shfl_xor(p1, 1);  p1 += __shfl_xor(p1, 2);
    p2 += __shfl_xor(p2, 1);  p2 += __shfl_xor(p2, 2);
    p3 += __shfl_xor(p3, 1);  p3 += __shfl_xor(p3, 2);

    // Branchless static select (no dynamic register indexing -> no scratch).
    float pq = (q == 0) ? p0 : ((q == 1) ? p1 : ((q == 2) ? p2 : p3));
    flow[e0 + q * ECHUNK] = pq + bias;

    // Scatter side-tasks: side = q>>1 (0=src, 1=dst), chunks (q&1), (q&1)+2.
    int side = q >> 1;
    int c1 = (q & 1), c2 = (q & 1) + 2;
    int ea = e0 + c1 * ECHUNK;
    int eb = e0 + c2 * ECHUNK;
    int sa = src[ea], da = dst[ea];
    int sb = src[eb], db = dst[eb];
    if (sa != da) {
        int idx = side ? da : sa;
        if (!settled[idx]) atomicMax(&max_ord[idx], 2 * ea + side);
    }
    if (sb != db) {
        int idx = side ? db : sb;
        if (!settled[idx]) atomicMax(&max_ord[idx], 2 * eb + side);
    }
}

// K3: per-node finalize — decode winning occurrence, gather its value.
__global__ void finalize_kernel(const int* __restrict__ src,
                                const float* __restrict__ flow,
                                const int* __restrict__ max_ord,
                                const float* __restrict__ conc_c,
                                const float* __restrict__ rsize_c,
                                float* __restrict__ out) {
    int n = blockIdx.x * blockDim.x + threadIdx.x;
    if (n >= N_NODES) return;
    int o = max_ord[n];
    if (o < 0) return;
    int e = o >> 1;
    float val = flow[e];
    float v;
    if ((o & 1) == 0) {
        v = val * conc_c[n] * rsize_c[n];            // src-side: src[e]==n
    } else {
        int s = src[e];
        v = val * conc_c[s] * rsize_c[n];            // dst-side
    }
    out[n] += v;
}

extern "C" void kernel_launch(void* const* d_in, const int* in_sizes, int n_in,
                              void* d_out, int out_size, void* d_ws, size_t ws_size,
                              hipStream_t stream) {
    const float* origin = (const float*)d_in[0];   // (N, 8, 3)
    const float* x      = (const float*)d_in[1];   // (E, 1, 16)
    const float* conv_w = (const float*)d_in[2];   // (1, 16, 1, 1)
    const float* conv_b = (const float*)d_in[3];   // (1,)
    const int*   eidx   = (const int*)d_in[4];     // (2, E)
    const int* src = eidx;
    const int* dst = eidx + E_EDGES;

    float* out  = (float*)d_out;          // [0, N): result; [N, N+E): flow
    float* flow = out + N_NODES;

    int*           max_ord = (int*)d_ws;                           // 400 KB
    float*         conc_c  = (float*)((char*)d_ws + 1 * 400 * 1024);
    float*         rsize_c = (float*)((char*)d_ws + 2 * 400 * 1024);
    unsigned char* settled = (unsigned char*)((char*)d_ws + 3 * 400 * 1024); // 100 KB

    table_init_kernel<<<(N_NODES / 4 + BLK - 1) / BLK, BLK, 0, stream>>>(
        (int4*)max_ord, (uint4*)settled);
    init_and_top_kernel<<<NODE_BLOCKS + TOP_BLOCKS, BLK, 0, stream>>>(
        origin, src, dst, out, conc_c, rsize_c, max_ord, settled);
    fused_flow_scatter_kernel<<<(QTHREADS + BLK - 1) / BLK, BLK, 0, stream>>>(
        (const float4*)x, conv_w, conv_b, src, dst, settled, flow, max_ord);
    finalize_kernel<<<(N_NODES + BLK - 1) / BLK, BLK, 0, stream>>>(
        src, flow, max_ord, conc_c, rsize_c, out);
}